// Round 17
// baseline (202.306 us; speedup 1.0000x reference)
//
#include <hip/hip_runtime.h>

typedef unsigned short u16;
typedef unsigned int u32;
typedef __bf16 bf16;
typedef bf16 bf16x8 __attribute__((ext_vector_type(8)));
typedef float f32x4 __attribute__((ext_vector_type(4)));
typedef float f32x16 __attribute__((ext_vector_type(16)));
typedef u16 u16x8 __attribute__((ext_vector_type(8)));
typedef u16 u16x4 __attribute__((ext_vector_type(4)));
typedef u32 u32x4 __attribute__((ext_vector_type(4)));

#define B_ 4
#define S_ 2048
#define H_ 1024
#define NH_ 16
#define HD_ 64
#define M_TOT (B_ * S_)          // 8192
#define N_TOT (3 * H_)           // 3072

// hardware 2^x: single quarter-rate v_exp_f32 (library exp2f costs ~10 VALU ops -> R5 regression)
#if __has_builtin(__builtin_amdgcn_exp2f)
#define EXP2(x) __builtin_amdgcn_exp2f(x)
#else
static __device__ __forceinline__ float exp2_hw(float x) {
    float r; asm("v_exp_f32 %0, %1" : "=v"(r) : "v"(x)); return r;
}
#define EXP2(x) exp2_hw(x)
#endif

__device__ __forceinline__ u16 f2bf(float f) {
    union { float f; unsigned u; } v; v.f = f;
    unsigned r = v.u + 0x7FFFu + ((v.u >> 16) & 1u);
    return (u16)(r >> 16);
}

__device__ __forceinline__ u32 cvt_pk_bf16(float a, float b) {
    u32 r;
    asm("v_cvt_pk_bf16_f32 %0, %1, %2" : "=v"(r) : "v"(a), "v"(b));
    return r;
}
__device__ __forceinline__ void perm32swap(u32& a, u32& b) {
    asm volatile("v_permlane32_swap_b32 %0, %1" : "+v"(a), "+v"(b));
}
__device__ __forceinline__ void gload16(const void* g, void* l) {
    __builtin_amdgcn_global_load_lds(
        (const __attribute__((address_space(1))) void*)g,
        (__attribute__((address_space(3))) void*)l, 16, 0, 0);
}
__device__ __forceinline__ void wait_vm0() { asm volatile("s_waitcnt vmcnt(0)" ::: "memory"); }
__device__ __forceinline__ void wait_vm2() { asm volatile("s_waitcnt vmcnt(2)" ::: "memory"); }
__device__ __forceinline__ void wait_vm3() { asm volatile("s_waitcnt vmcnt(3)" ::: "memory"); }

// ---------------- fused fp32 -> bf16 conversion (X + Wq + Wk + Wv in one launch) ----------------
__global__ __launch_bounds__(256) void cvt_all(
    const float* __restrict__ x, const float* __restrict__ wq,
    const float* __restrict__ wk, const float* __restrict__ wv,
    u16* __restrict__ xb, u16* __restrict__ wb) {
    const int X4 = (M_TOT * H_) / 4;     // 2097152
    const int W4 = (H_ * H_) / 4;        // 262144 = 2^18
    const int total = X4 + 3 * W4;
    int i = blockIdx.x * blockDim.x + threadIdx.x;
    int stride = gridDim.x * blockDim.x;
    for (; i < total; i += stride) {
        const float* src; u16* dst; int off;
        if (i < X4) { src = x; dst = xb; off = i; }
        else {
            int j = i - X4;
            int w = j >> 18;
            off = j & (W4 - 1);
            src = (w == 0) ? wq : (w == 1) ? wk : wv;
            dst = wb + w * (H_ * H_);
        }
        float4 v = ((const float4*)src)[off];
        u16x4 o = { f2bf(v.x), f2bf(v.y), f2bf(v.z), f2bf(v.w) };
        *(u16x4*)&dst[off * 4] = o;
    }
}

// ---------------- fused QKV GEMM: 256x128 tile, tri-buffer + counted vmcnt + T2 LDS swizzle ----------------
// NOTE (R15 lesson): keep __launch_bounds__(512,2). Tightening to (512,4) forces VGPR<=128 ->
// scratch spills, and scratch ops increment vmcnt -> the counted wait_vm3() accounting breaks
// -> data race on LDS tiles (absmax 6.7). Never tighten bounds on counted-vmcnt kernels.
#define GNT 32   // K-steps

__global__ __launch_bounds__(512, 2) void qkv_gemm(
    const u16* __restrict__ X, const u16* __restrict__ W,
    const float* __restrict__ bq, const float* __restrict__ bk, const float* __restrict__ bv,
    u16* __restrict__ Q, u16* __restrict__ Ko, u16* __restrict__ Vt) {
    __shared__ __align__(16) u16 As[3][256 * 32];   // 3 x 16KB
    __shared__ __align__(16) u16 Bs[3][128 * 32];   // 3 x 8KB

    const int tid = threadIdx.x;
    const int lane = tid & 63;
    const int wave = tid >> 6;          // 0..7
    const int l31 = lane & 31;
    const int hi = lane >> 5;
    const int mb = blockIdx.x & 31;     // 32 m-blocks
    const int nb = blockIdx.x >> 5;     // 24 n-blocks
    const int m0 = mb * 256;
    const int n0 = nb * 128;
    const int wr = (wave >> 1) * 64;    // 4 M-waves
    const int wc = (wave & 1) * 64;     // 2 N-waves

    f32x16 acc[2][2];
#pragma unroll
    for (int mf = 0; mf < 2; mf++)
#pragma unroll
        for (int nf = 0; nf < 2; nf++)
#pragma unroll
            for (int i = 0; i < 16; i++) acc[mf][nf][i] = 0.f;

    // staging chunk: row = tid>>2, slot = tid&3 (4 x 16B slots per 64B row).
    // SOURCE pre-swizzle: slot' = slot ^ (row&3); read XOR-swizzled (rule #21).
    const int raA = tid >> 2;
    const u32 scol = (u32)(((tid & 3) ^ (raA & 3)) * 16);
    const char* gA0 = (const char*)X + (size_t)(m0 + raA) * (H_ * 2) + scol;
    const char* gA1 = (const char*)X + (size_t)(m0 + 128 + raA) * (H_ * 2) + scol;
    const char* gB0 = (const char*)W + (size_t)(n0 + raA) * (H_ * 2) + scol;
    char* lA = (char*)&As[0][0] + wave * 1024;
    char* lB = (char*)&Bs[0][0] + wave * 1024;

    auto stage = [&](int t) {
        char* dA = lA + (t % 3) * 16384;
        char* dB = lB + (t % 3) * 8192;
        gload16(gA0 + t * 64, dA);
        gload16(gA1 + t * 64, dA + 8192);
        gload16(gB0 + t * 64, dB);
    };

    const u32 swzG = (u32)((l31 & 3) << 4);   // read-side XOR; row&3 == l31&3

    // prologue: 2 tiles in flight
    stage(0);
    stage(1);

    for (int t = 0; t < GNT; ++t) {
        if (t < GNT - 1) wait_vm3();    // own 3 loads of tile t landed; tile t+1 stays in flight
        else             wait_vm0();
        __builtin_amdgcn_s_barrier();
        if (t + 2 < GNT) stage(t + 2);  // clobbers buf[(t-1)%3]: fully consumed before barrier

        const char* Ab = (const char*)&As[t % 3][0];
        const char* Bb = (const char*)&Bs[t % 3][0];
        bf16x8 a[2][2], bfr[2][2];
#pragma unroll
        for (int mf = 0; mf < 2; mf++)
#pragma unroll
            for (int ks = 0; ks < 2; ks++)
                a[mf][ks] = *(const bf16x8*)(Ab + (wr + mf * 32 + l31) * 64 +
                                             (((u32)(ks * 32 + hi * 16)) ^ swzG));
#pragma unroll
        for (int nf = 0; nf < 2; nf++)
#pragma unroll
            for (int ks = 0; ks < 2; ks++)
                bfr[nf][ks] = *(const bf16x8*)(Bb + (wc + nf * 32 + l31) * 64 +
                                               (((u32)(ks * 32 + hi * 16)) ^ swzG));
#pragma unroll
        for (int mf = 0; mf < 2; mf++)
#pragma unroll
            for (int nf = 0; nf < 2; nf++)
#pragma unroll
                for (int ks = 0; ks < 2; ks++)
                    acc[mf][nf] = __builtin_amdgcn_mfma_f32_32x32x16_bf16(
                        a[mf][ks], bfr[nf][ks], acc[mf][nf], 0, 0, 0);
    }

    // epilogue: C/D 32x32 layout: col = lane&31, row = (r&3) + 8*(r>>2) + 4*hi
    const float QS = 0.125f * 1.44269504f;
    const int which = n0 >> 10;                     // uniform per block
    const float* bp = (which == 0) ? bq : (which == 1) ? bk : bv;
#pragma unroll
    for (int nf = 0; nf < 2; nf++) {
        int ng = n0 + wc + nf * 32 + l31;
        int nn = ng & 1023;
        float bias = bp[nn];
        int h = nn >> 6, d = nn & 63;
#pragma unroll
        for (int mf = 0; mf < 2; mf++) {
#pragma unroll
            for (int q = 0; q < 4; q++) {
                int mrow0 = m0 + wr + mf * 32 + 8 * q + 4 * hi;
                int bb = mrow0 >> 11, s0 = mrow0 & 2047;
                if (which == 2) {
                    u16x4 pack;
#pragma unroll
                    for (int j = 0; j < 4; j++) pack[j] = f2bf(acc[mf][nf][q * 4 + j] + bias);
                    *(u16x4*)&Vt[((((size_t)bb * NH_ + h) * HD_) + d) * S_ + s0] = pack;
                } else {
                    u16* dst = (which == 0) ? Q : Ko;
                    float scale = (which == 0) ? QS : 1.0f;
#pragma unroll
                    for (int j = 0; j < 4; j++) {
                        float v = (acc[mf][nf][q * 4 + j] + bias) * scale;
                        dst[((((size_t)bb * NH_ + h) * S_) + s0 + j) * HD_ + d] = f2bf(v);
                    }
                }
            }
        }
    }
}

// ---------------- flash attention: R16 compute + tri-buffer counted-vmcnt staging (T4 isolated) ----------------
// Change vs R16: K/V triple-buffered (48KB LDS, still 2 blocks/CU - grid-limited), wait_vm2
// instead of wait_vm0 in steady state -> tile t+1's 2 DMA loads stay in flight across the
// barrier. Mask stays in global (mz fast path); VGPR ~64-72 << 128 cap so no spill can
// poison the vmcnt count (R15 lesson).
#define KVB 64
#define NT_ (S_ / KVB)

__global__ __launch_bounds__(512, 4) void attn(
    const u16* __restrict__ Q, const u16* __restrict__ K, const u16* __restrict__ Vt,
    const float* __restrict__ mask, float* __restrict__ out) {
    const int head = blockIdx.x & 63;
    const int qb = blockIdx.x >> 6;
    const int b = head >> 4, h = head & 15;
    const int q0 = qb * 256;
    const int tid = threadIdx.x;
    const int lane = tid & 63;
    const int wave = tid >> 6;          // 0..7
    const int l31 = lane & 31;
    const int hi = lane >> 5;

    const u16* Qh = Q + (size_t)head * S_ * HD_;
    const u16* Kh = K + (size_t)head * S_ * HD_;
    const u16* Vh = Vt + (size_t)head * HD_ * S_;   // [d][s]

    __shared__ __align__(16) u16 Kl[3][KVB * HD_];  // 3 x 8KB
    __shared__ __align__(16) u16 Vl[3][HD_ * KVB];  // 3 x 8KB
    __shared__ int snz;

    // ---- mask all-zero detection ----
    if (tid == 0) snz = 0;
    __syncthreads();
    {
        int nz = 0;
        const f32x4* m4 = (const f32x4*)(mask + (size_t)b * S_);
        for (int i = tid; i < S_ / 4; i += 512) {
            f32x4 v = m4[i];
            nz |= (v[0] != 0.f) | (v[1] != 0.f) | (v[2] != 0.f) | (v[3] != 0.f);
        }
        if (__any(nz) && lane == 0) atomicOr(&snz, 1);
    }

    // ---- Q fragments (B-operand): lane holds q=lane&31 ----
    bf16x8 qf[4];
    {
        const u16* qp = &Qh[(size_t)(q0 + wave * 32 + l31) * HD_ + hi * 8];
        qf[0] = *(const bf16x8*)(qp);
        qf[1] = *(const bf16x8*)(qp + 16);
        qf[2] = *(const bf16x8*)(qp + 32);
        qf[3] = *(const bf16x8*)(qp + 48);
    }
    __syncthreads();   // drains Q loads + snz writes (compiler emits vmcnt(0) lgkmcnt(0))
    const bool mz = (snz == 0);
    const float* mrow = mask + (size_t)b * S_;
    const float LOG2E = 1.44269504f;

    // ---- staging: each of 512 threads stages ONE 16B K-chunk + ONE 16B V-chunk per tile ----
    const int rc = tid >> 3;
    const u32 sc16 = (u32)(((tid & 7) ^ (rc & 7)) * 16);
    const char* kSrc = (const char*)Kh + (size_t)rc * 128 + sc16;
    const char* vSrc = (const char*)Vh + (size_t)rc * (S_ * 2) + sc16;
    char* dK = (char*)&Kl[0][0] + wave * 1024;   // + (t%3)*8192
    char* dV = (char*)&Vl[0][0] + wave * 1024;

    auto stage = [&](int t) {
        gload16(kSrc + (size_t)t * 8192, dK + (t % 3) * 8192);   // K tile t: 64 rows x 128B
        gload16(vSrc + (size_t)t * 128,  dV + (t % 3) * 8192);   // V^T tile t: 64 kv cols x 2B
    };

    const u32 swzR = (u32)((l31 & 7) << 4);
    const u32 rowB = (u32)(l31 * 128);

    f32x16 oacc[2];
#pragma unroll
    for (int dh = 0; dh < 2; dh++)
#pragma unroll
        for (int i = 0; i < 16; i++) oacc[dh][i] = 0.f;
    float m = -1e30f, l = 0.f;

    // prologue: 2 tiles in flight
    stage(0);
    stage(1);

    for (int t = 0; t < NT_; ++t) {
        const int kv0 = t * KVB;
        if (t < NT_ - 1) wait_vm2();    // own 2 loads of tile t landed; tile t+1 stays in flight
        else             wait_vm0();
        __builtin_amdgcn_s_barrier();
        if (t + 2 < NT_) stage(t + 2);  // clobbers buf[(t-1)%3]: fully consumed before barrier

        const char* KB = (const char*)&Kl[t % 3][0];
        const char* VB = (const char*)&Vl[t % 3][0];

        // ---- QK^T: S^T[kv][q], 2 kv-groups x 4 d-steps ----
        f32x16 sc[2];
#pragma unroll
        for (int g = 0; g < 2; g++) {
            f32x16 c;
#pragma unroll
            for (int i = 0; i < 16; i++) c[i] = 0.f;
#pragma unroll
            for (int dk = 0; dk < 4; dk++) {
                bf16x8 kf = *(const bf16x8*)(KB + g * 4096 + rowB +
                                             (((u32)(dk * 32 + hi * 16)) ^ swzR));
                c = __builtin_amdgcn_mfma_f32_32x32x16_bf16(kf, qf[dk], c, 0, 0, 0);
            }
            sc[g] = c;
        }

        // ---- additive mask (skipped when mask is all-zero; loads compiler-drained on use) ----
        if (!mz) {
#pragma unroll
            for (int g = 0; g < 2; g++)
#pragma unroll
                for (int c4 = 0; c4 < 4; c4++) {
                    f32x4 mk = *(const f32x4*)&mrow[kv0 + g * 32 + c4 * 8 + hi * 4];
#pragma unroll
                    for (int e = 0; e < 4; e++) sc[g][c4 * 4 + e] += mk[e] * LOG2E;
                }
        }

        // ---- row max + defer-rescale (THR=30 in log2 domain) ----
        float tm = sc[0][0];
#pragma unroll
        for (int i = 1; i < 16; i++) tm = fmaxf(tm, sc[0][i]);
#pragma unroll
        for (int i = 0; i < 16; i++) tm = fmaxf(tm, sc[1][i]);
        tm = fmaxf(tm, __shfl_xor(tm, 32, 64));
        if (tm > m + 30.f) {
            float fac = EXP2(m - tm);
            l *= fac;
#pragma unroll
            for (int dh = 0; dh < 2; dh++)
#pragma unroll
                for (int i = 0; i < 16; i++) oacc[dh][i] *= fac;
            m = tm;
        }

        // ---- P = 2^(s-m); l-sum in-lane ----
        float l0 = 0.f, l1 = 0.f, l2 = 0.f, l3 = 0.f;
#pragma unroll
        for (int g = 0; g < 2; g++)
#pragma unroll
            for (int i = 0; i < 16; i += 4) {
                float p0 = EXP2(sc[g][i + 0] - m);
                float p1 = EXP2(sc[g][i + 1] - m);
                float p2 = EXP2(sc[g][i + 2] - m);
                float p3 = EXP2(sc[g][i + 3] - m);
                sc[g][i + 0] = p0; sc[g][i + 1] = p1;
                sc[g][i + 2] = p2; sc[g][i + 3] = p3;
                l0 += p0; l1 += p1; l2 += p2; l3 += p3;
            }
        l += (l0 + l1) + (l2 + l3);

        // ---- PV: per 16-kv subtile, P^T B-frag via cvt_pk + permlane32_swap ----
#pragma unroll
        for (int s = 0; s < 4; s++) {
            const int g = s >> 1, r8 = (s & 1) * 8;
            u32 pkA0 = cvt_pk_bf16(sc[g][r8 + 0], sc[g][r8 + 1]);
            u32 pkA1 = cvt_pk_bf16(sc[g][r8 + 2], sc[g][r8 + 3]);
            u32 pkB0 = cvt_pk_bf16(sc[g][r8 + 4], sc[g][r8 + 5]);
            u32 pkB1 = cvt_pk_bf16(sc[g][r8 + 6], sc[g][r8 + 7]);
            perm32swap(pkA0, pkB0);
            perm32swap(pkA1, pkB1);
            union { u32x4 w; bf16x8 v; } pu;
            pu.w = (u32x4){ pkA0, pkA1, pkB0, pkB1 };
            bf16x8 pf = pu.v;
#pragma unroll
            for (int dh = 0; dh < 2; dh++) {
                bf16x8 vf = *(const bf16x8*)(VB + dh * 4096 + rowB +
                                             (((u32)(s * 32 + hi * 16)) ^ swzR));
                oacc[dh] = __builtin_amdgcn_mfma_f32_32x32x16_bf16(vf, pf, oacc[dh], 0, 0, 0);
            }
        }
    }

    // ---- epilogue: lane owns q-row ----
    float lt = l + __shfl_xor(l, 32, 64);
    float inv = 1.0f / lt;
    const int q = q0 + wave * 32 + l31;
    float* orow = out + ((size_t)b * S_ + q) * H_ + h * HD_;
#pragma unroll
    for (int dh = 0; dh < 2; dh++)
#pragma unroll
        for (int c4 = 0; c4 < 4; c4++) {
            f32x4 v;
#pragma unroll
            for (int e = 0; e < 4; e++) v[e] = oacc[dh][c4 * 4 + e] * inv;
            *(f32x4*)&orow[dh * 32 + c4 * 8 + hi * 4] = v;
        }
}

// ---------------- launch ----------------
extern "C" void kernel_launch(void* const* d_in, const int* in_sizes, int n_in,
                              void* d_out, int out_size, void* d_ws, size_t ws_size,
                              hipStream_t stream) {
    const float* hs   = (const float*)d_in[0];
    const float* mask = (const float*)d_in[1];
    const float* wq   = (const float*)d_in[2];
    const float* bq   = (const float*)d_in[3];
    const float* wk   = (const float*)d_in[4];
    const float* bk   = (const float*)d_in[5];
    const float* wv   = (const float*)d_in[6];
    const float* bv   = (const float*)d_in[7];
    float* out = (float*)d_out;

    char* ws = (char*)d_ws;
    u16* Xb = (u16*)ws;                                   // 16 MB
    u16* Wb = (u16*)(ws + 16777216);                      // 6 MB
    u16* Qb = (u16*)(ws + 23068672);                      // 16 MB
    u16* Kb = (u16*)(ws + 39845888);                      // 16 MB
    u16* Vb = (u16*)(ws + 56623104);                      // 16 MB (V^T layout)

    cvt_all<<<2048, 256, 0, stream>>>(hs, wq, wk, wv, Xb, Wb);

    // XCD swizzle (T1): bid = nb*32 + mb -> all n-blocks of an A-panel on one XCD
    qkv_gemm<<<(N_TOT / 128) * (M_TOT / 256), 512, 0, stream>>>(
        Xb, Wb, bq, bk, bv, Qb, Kb, Vb);

    // XCD swizzle (T1): bid = qb*64 + head -> all q-blocks of a head on one XCD
    attn<<<(S_ / 256) * (B_ * NH_), 512, 0, stream>>>(Qb, Kb, Vb, mask, out);
}

// Round 18
// 192.859 us; speedup vs baseline: 1.0490x; 1.0490x over previous
//
#include <hip/hip_runtime.h>

typedef unsigned short u16;
typedef unsigned int u32;
typedef __bf16 bf16;
typedef bf16 bf16x8 __attribute__((ext_vector_type(8)));
typedef float f32x4 __attribute__((ext_vector_type(4)));
typedef float f32x16 __attribute__((ext_vector_type(16)));
typedef u16 u16x8 __attribute__((ext_vector_type(8)));
typedef u16 u16x4 __attribute__((ext_vector_type(4)));
typedef u32 u32x4 __attribute__((ext_vector_type(4)));

#define B_ 4
#define S_ 2048
#define H_ 1024
#define NH_ 16
#define HD_ 64
#define M_TOT (B_ * S_)          // 8192
#define N_TOT (3 * H_)           // 3072

// hardware 2^x: single quarter-rate v_exp_f32 (library exp2f costs ~10 VALU ops -> R5 regression)
#if __has_builtin(__builtin_amdgcn_exp2f)
#define EXP2(x) __builtin_amdgcn_exp2f(x)
#else
static __device__ __forceinline__ float exp2_hw(float x) {
    float r; asm("v_exp_f32 %0, %1" : "=v"(r) : "v"(x)); return r;
}
#define EXP2(x) exp2_hw(x)
#endif

__device__ __forceinline__ u16 f2bf(float f) {
    union { float f; unsigned u; } v; v.f = f;
    unsigned r = v.u + 0x7FFFu + ((v.u >> 16) & 1u);
    return (u16)(r >> 16);
}

__device__ __forceinline__ u32 cvt_pk_bf16(float a, float b) {
    u32 r;
    asm("v_cvt_pk_bf16_f32 %0, %1, %2" : "=v"(r) : "v"(a), "v"(b));
    return r;
}
__device__ __forceinline__ void perm32swap(u32& a, u32& b) {
    asm volatile("v_permlane32_swap_b32 %0, %1" : "+v"(a), "+v"(b));
}
__device__ __forceinline__ void gload16(const void* g, void* l) {
    __builtin_amdgcn_global_load_lds(
        (const __attribute__((address_space(1))) void*)g,
        (__attribute__((address_space(3))) void*)l, 16, 0, 0);
}
__device__ __forceinline__ void wait_vm0() { asm volatile("s_waitcnt vmcnt(0)" ::: "memory"); }
__device__ __forceinline__ void wait_vm3() { asm volatile("s_waitcnt vmcnt(3)" ::: "memory"); }

// ---------------- fused fp32 -> bf16 conversion (X + Wq + Wk + Wv in one launch) ----------------
__global__ __launch_bounds__(256) void cvt_all(
    const float* __restrict__ x, const float* __restrict__ wq,
    const float* __restrict__ wk, const float* __restrict__ wv,
    u16* __restrict__ xb, u16* __restrict__ wb) {
    const int X4 = (M_TOT * H_) / 4;     // 2097152
    const int W4 = (H_ * H_) / 4;        // 262144 = 2^18
    const int total = X4 + 3 * W4;
    int i = blockIdx.x * blockDim.x + threadIdx.x;
    int stride = gridDim.x * blockDim.x;
    for (; i < total; i += stride) {
        const float* src; u16* dst; int off;
        if (i < X4) { src = x; dst = xb; off = i; }
        else {
            int j = i - X4;
            int w = j >> 18;
            off = j & (W4 - 1);
            src = (w == 0) ? wq : (w == 1) ? wk : wv;
            dst = wb + w * (H_ * H_);
        }
        float4 v = ((const float4*)src)[off];
        u16x4 o = { f2bf(v.x), f2bf(v.y), f2bf(v.z), f2bf(v.w) };
        *(u16x4*)&dst[off * 4] = o;
    }
}

// ---------------- fused QKV GEMM: 256x128 tile, tri-buffer + counted vmcnt + T2 LDS swizzle ----------------
// NOTE (R15 lesson): keep __launch_bounds__(512,2). Tightening to (512,4) forces VGPR<=128 ->
// scratch spills, and scratch ops increment vmcnt -> the counted wait_vm3() accounting breaks
// -> data race on LDS tiles (absmax 6.7). Never tighten bounds on counted-vmcnt kernels.
#define GNT 32   // K-steps

__global__ __launch_bounds__(512, 2) void qkv_gemm(
    const u16* __restrict__ X, const u16* __restrict__ W,
    const float* __restrict__ bq, const float* __restrict__ bk, const float* __restrict__ bv,
    u16* __restrict__ Q, u16* __restrict__ Ko, u16* __restrict__ Vt) {
    __shared__ __align__(16) u16 As[3][256 * 32];   // 3 x 16KB
    __shared__ __align__(16) u16 Bs[3][128 * 32];   // 3 x 8KB

    const int tid = threadIdx.x;
    const int lane = tid & 63;
    const int wave = tid >> 6;          // 0..7
    const int l31 = lane & 31;
    const int hi = lane >> 5;
    const int mb = blockIdx.x & 31;     // 32 m-blocks
    const int nb = blockIdx.x >> 5;     // 24 n-blocks
    const int m0 = mb * 256;
    const int n0 = nb * 128;
    const int wr = (wave >> 1) * 64;    // 4 M-waves
    const int wc = (wave & 1) * 64;     // 2 N-waves

    f32x16 acc[2][2];
#pragma unroll
    for (int mf = 0; mf < 2; mf++)
#pragma unroll
        for (int nf = 0; nf < 2; nf++)
#pragma unroll
            for (int i = 0; i < 16; i++) acc[mf][nf][i] = 0.f;

    // staging chunk: row = tid>>2, slot = tid&3 (4 x 16B slots per 64B row).
    // SOURCE pre-swizzle: slot' = slot ^ (row&3); read XOR-swizzled (rule #21).
    const int raA = tid >> 2;
    const u32 scol = (u32)(((tid & 3) ^ (raA & 3)) * 16);
    const char* gA0 = (const char*)X + (size_t)(m0 + raA) * (H_ * 2) + scol;
    const char* gA1 = (const char*)X + (size_t)(m0 + 128 + raA) * (H_ * 2) + scol;
    const char* gB0 = (const char*)W + (size_t)(n0 + raA) * (H_ * 2) + scol;
    char* lA = (char*)&As[0][0] + wave * 1024;
    char* lB = (char*)&Bs[0][0] + wave * 1024;

    auto stage = [&](int t) {
        char* dA = lA + (t % 3) * 16384;
        char* dB = lB + (t % 3) * 8192;
        gload16(gA0 + t * 64, dA);
        gload16(gA1 + t * 64, dA + 8192);
        gload16(gB0 + t * 64, dB);
    };

    const u32 swzG = (u32)((l31 & 3) << 4);   // read-side XOR; row&3 == l31&3

    // prologue: 2 tiles in flight
    stage(0);
    stage(1);

    for (int t = 0; t < GNT; ++t) {
        if (t < GNT - 1) wait_vm3();    // own 3 loads of tile t landed; tile t+1 stays in flight
        else             wait_vm0();
        __builtin_amdgcn_s_barrier();
        if (t + 2 < GNT) stage(t + 2);  // clobbers buf[(t-1)%3]: fully consumed before barrier

        const char* Ab = (const char*)&As[t % 3][0];
        const char* Bb = (const char*)&Bs[t % 3][0];
        bf16x8 a[2][2], bfr[2][2];
#pragma unroll
        for (int mf = 0; mf < 2; mf++)
#pragma unroll
            for (int ks = 0; ks < 2; ks++)
                a[mf][ks] = *(const bf16x8*)(Ab + (wr + mf * 32 + l31) * 64 +
                                             (((u32)(ks * 32 + hi * 16)) ^ swzG));
#pragma unroll
        for (int nf = 0; nf < 2; nf++)
#pragma unroll
            for (int ks = 0; ks < 2; ks++)
                bfr[nf][ks] = *(const bf16x8*)(Bb + (wc + nf * 32 + l31) * 64 +
                                               (((u32)(ks * 32 + hi * 16)) ^ swzG));
#pragma unroll
        for (int mf = 0; mf < 2; mf++)
#pragma unroll
            for (int nf = 0; nf < 2; nf++)
#pragma unroll
                for (int ks = 0; ks < 2; ks++)
                    acc[mf][nf] = __builtin_amdgcn_mfma_f32_32x32x16_bf16(
                        a[mf][ks], bfr[nf][ks], acc[mf][nf], 0, 0, 0);
    }

    // epilogue: C/D 32x32 layout: col = lane&31, row = (r&3) + 8*(r>>2) + 4*hi
    const float QS = 0.125f * 1.44269504f;
    const int which = n0 >> 10;                     // uniform per block
    const float* bp = (which == 0) ? bq : (which == 1) ? bk : bv;
#pragma unroll
    for (int nf = 0; nf < 2; nf++) {
        int ng = n0 + wc + nf * 32 + l31;
        int nn = ng & 1023;
        float bias = bp[nn];
        int h = nn >> 6, d = nn & 63;
#pragma unroll
        for (int mf = 0; mf < 2; mf++) {
#pragma unroll
            for (int q = 0; q < 4; q++) {
                int mrow0 = m0 + wr + mf * 32 + 8 * q + 4 * hi;
                int bb = mrow0 >> 11, s0 = mrow0 & 2047;
                if (which == 2) {
                    u16x4 pack;
#pragma unroll
                    for (int j = 0; j < 4; j++) pack[j] = f2bf(acc[mf][nf][q * 4 + j] + bias);
                    *(u16x4*)&Vt[((((size_t)bb * NH_ + h) * HD_) + d) * S_ + s0] = pack;
                } else {
                    u16* dst = (which == 0) ? Q : Ko;
                    float scale = (which == 0) ? QS : 1.0f;
#pragma unroll
                    for (int j = 0; j < 4; j++) {
                        float v = (acc[mf][nf][q * 4 + j] + bias) * scale;
                        dst[((((size_t)bb * NH_ + h) * S_) + s0 + j) * HD_ + d] = f2bf(v);
                    }
                }
            }
        }
    }
}

// ---------------- flash attention: R12/R14/R16-proven kernel (KVB=64, dbuf, full drain) ----------------
// NOTE (R17 lesson): counted-vmcnt tri-buffer REGRESSES this kernel (100.4 -> 108.4 us).
// At 2 blocks/CU x 8 waves with only 2 DMA loads/tile, wave-level TLP already hides the DMA
// latency; deeper pipelining only adds SGPR/addressing overhead. Keep the simple dbuf drain.
#define KVB 64
#define NT_ (S_ / KVB)

__global__ __launch_bounds__(512, 4) void attn(
    const u16* __restrict__ Q, const u16* __restrict__ K, const u16* __restrict__ Vt,
    const float* __restrict__ mask, float* __restrict__ out) {
    const int head = blockIdx.x & 63;
    const int qb = blockIdx.x >> 6;
    const int b = head >> 4, h = head & 15;
    const int q0 = qb * 256;
    const int tid = threadIdx.x;
    const int lane = tid & 63;
    const int wave = tid >> 6;          // 0..7
    const int l31 = lane & 31;
    const int hi = lane >> 5;

    const u16* Qh = Q + (size_t)head * S_ * HD_;
    const u16* Kh = K + (size_t)head * S_ * HD_;
    const u16* Vh = Vt + (size_t)head * HD_ * S_;   // [d][s]

    __shared__ __align__(16) u16 Kl[2][KVB * HD_];  // 2 x 8KB
    __shared__ __align__(16) u16 Vl[2][HD_ * KVB];  // 2 x 8KB
    __shared__ int snz;

    // ---- mask all-zero detection ----
    if (tid == 0) snz = 0;
    __syncthreads();
    {
        int nz = 0;
        const f32x4* m4 = (const f32x4*)(mask + (size_t)b * S_);
        for (int i = tid; i < S_ / 4; i += 512) {
            f32x4 v = m4[i];
            nz |= (v[0] != 0.f) | (v[1] != 0.f) | (v[2] != 0.f) | (v[3] != 0.f);
        }
        if (__any(nz) && lane == 0) atomicOr(&snz, 1);
    }

    // ---- Q fragments (B-operand): lane holds q=lane&31 ----
    bf16x8 qf[4];
    {
        const u16* qp = &Qh[(size_t)(q0 + wave * 32 + l31) * HD_ + hi * 8];
        qf[0] = *(const bf16x8*)(qp);
        qf[1] = *(const bf16x8*)(qp + 16);
        qf[2] = *(const bf16x8*)(qp + 32);
        qf[3] = *(const bf16x8*)(qp + 48);
    }
    __syncthreads();
    const bool mz = (snz == 0);
    const float* mrow = mask + (size_t)b * S_;
    const float LOG2E = 1.44269504f;

    // ---- staging: each of 512 threads stages ONE 16B K-chunk + ONE 16B V-chunk ----
    const int rc = tid >> 3;
    const u32 sc16 = (u32)(((tid & 7) ^ (rc & 7)) * 16);
    const char* kSrc = (const char*)Kh + (size_t)rc * 128 + sc16;
    const char* vSrc = (const char*)Vh + (size_t)rc * (S_ * 2) + sc16;
    char* dK = (char*)&Kl[0][0] + wave * 1024;   // + cur*8192
    char* dV = (char*)&Vl[0][0] + wave * 1024;

    const u32 swzR = (u32)((l31 & 7) << 4);
    const u32 rowB = (u32)(l31 * 128);

    f32x16 oacc[2];
#pragma unroll
    for (int dh = 0; dh < 2; dh++)
#pragma unroll
        for (int i = 0; i < 16; i++) oacc[dh][i] = 0.f;
    float m = -1e30f, l = 0.f;

    // prologue stage tile 0 -> buf0
    gload16(kSrc, dK);
    gload16(vSrc, dV);

    for (int t = 0; t < NT_; ++t) {
        const int kv0 = t * KVB;
        const int cur = t & 1;
        wait_vm0();
        __builtin_amdgcn_s_barrier();
        if (t + 1 < NT_) {
            gload16(kSrc + (size_t)(kv0 + KVB) * 128, dK + (cur ^ 1) * 8192);
            gload16(vSrc + (size_t)(kv0 + KVB) * 2,   dV + (cur ^ 1) * 8192);
        }
        const char* KB = (const char*)&Kl[cur][0];
        const char* VB = (const char*)&Vl[cur][0];

        // ---- QK^T: S^T[kv][q], 2 kv-groups x 4 d-steps ----
        f32x16 sc[2];
#pragma unroll
        for (int g = 0; g < 2; g++) {
            f32x16 c;
#pragma unroll
            for (int i = 0; i < 16; i++) c[i] = 0.f;
#pragma unroll
            for (int dk = 0; dk < 4; dk++) {
                bf16x8 kf = *(const bf16x8*)(KB + g * 4096 + rowB +
                                             (((u32)(dk * 32 + hi * 16)) ^ swzR));
                c = __builtin_amdgcn_mfma_f32_32x32x16_bf16(kf, qf[dk], c, 0, 0, 0);
            }
            sc[g] = c;
        }

        // ---- additive mask (skipped when mask is all-zero) ----
        if (!mz) {
#pragma unroll
            for (int g = 0; g < 2; g++)
#pragma unroll
                for (int c4 = 0; c4 < 4; c4++) {
                    f32x4 mk = *(const f32x4*)&mrow[kv0 + g * 32 + c4 * 8 + hi * 4];
#pragma unroll
                    for (int e = 0; e < 4; e++) sc[g][c4 * 4 + e] += mk[e] * LOG2E;
                }
        }

        // ---- row max + defer-rescale (THR=30 in log2 domain) ----
        float tm = sc[0][0];
#pragma unroll
        for (int i = 1; i < 16; i++) tm = fmaxf(tm, sc[0][i]);
#pragma unroll
        for (int i = 0; i < 16; i++) tm = fmaxf(tm, sc[1][i]);
        tm = fmaxf(tm, __shfl_xor(tm, 32, 64));
        if (tm > m + 30.f) {
            float fac = EXP2(m - tm);
            l *= fac;
#pragma unroll
            for (int dh = 0; dh < 2; dh++)
#pragma unroll
                for (int i = 0; i < 16; i++) oacc[dh][i] *= fac;
            m = tm;
        }

        // ---- P = 2^(s-m); l-sum in-lane ----
        float l0 = 0.f, l1 = 0.f, l2 = 0.f, l3 = 0.f;
#pragma unroll
        for (int g = 0; g < 2; g++)
#pragma unroll
            for (int i = 0; i < 16; i += 4) {
                float p0 = EXP2(sc[g][i + 0] - m);
                float p1 = EXP2(sc[g][i + 1] - m);
                float p2 = EXP2(sc[g][i + 2] - m);
                float p3 = EXP2(sc[g][i + 3] - m);
                sc[g][i + 0] = p0; sc[g][i + 1] = p1;
                sc[g][i + 2] = p2; sc[g][i + 3] = p3;
                l0 += p0; l1 += p1; l2 += p2; l3 += p3;
            }
        l += (l0 + l1) + (l2 + l3);

        // ---- PV: per 16-kv subtile, P^T B-frag via cvt_pk + permlane32_swap ----
#pragma unroll
        for (int s = 0; s < 4; s++) {
            const int g = s >> 1, r8 = (s & 1) * 8;
            u32 pkA0 = cvt_pk_bf16(sc[g][r8 + 0], sc[g][r8 + 1]);
            u32 pkA1 = cvt_pk_bf16(sc[g][r8 + 2], sc[g][r8 + 3]);
            u32 pkB0 = cvt_pk_bf16(sc[g][r8 + 4], sc[g][r8 + 5]);
            u32 pkB1 = cvt_pk_bf16(sc[g][r8 + 6], sc[g][r8 + 7]);
            perm32swap(pkA0, pkB0);
            perm32swap(pkA1, pkB1);
            union { u32x4 w; bf16x8 v; } pu;
            pu.w = (u32x4){ pkA0, pkA1, pkB0, pkB1 };
            bf16x8 pf = pu.v;
#pragma unroll
            for (int dh = 0; dh < 2; dh++) {
                bf16x8 vf = *(const bf16x8*)(VB + dh * 4096 + rowB +
                                             (((u32)(s * 32 + hi * 16)) ^ swzR));
                oacc[dh] = __builtin_amdgcn_mfma_f32_32x32x16_bf16(vf, pf, oacc[dh], 0, 0, 0);
            }
        }
    }

    // ---- epilogue: lane owns q-row ----
    float lt = l + __shfl_xor(l, 32, 64);
    float inv = 1.0f / lt;
    const int q = q0 + wave * 32 + l31;
    float* orow = out + ((size_t)b * S_ + q) * H_ + h * HD_;
#pragma unroll
    for (int dh = 0; dh < 2; dh++)
#pragma unroll
        for (int c4 = 0; c4 < 4; c4++) {
            f32x4 v;
#pragma unroll
            for (int e = 0; e < 4; e++) v[e] = oacc[dh][c4 * 4 + e] * inv;
            *(f32x4*)&orow[dh * 32 + c4 * 8 + hi * 4] = v;
        }
}

// ---------------- launch ----------------
extern "C" void kernel_launch(void* const* d_in, const int* in_sizes, int n_in,
                              void* d_out, int out_size, void* d_ws, size_t ws_size,
                              hipStream_t stream) {
    const float* hs   = (const float*)d_in[0];
    const float* mask = (const float*)d_in[1];
    const float* wq   = (const float*)d_in[2];
    const float* bq   = (const float*)d_in[3];
    const float* wk   = (const float*)d_in[4];
    const float* bk   = (const float*)d_in[5];
    const float* wv   = (const float*)d_in[6];
    const float* bv   = (const float*)d_in[7];
    float* out = (float*)d_out;

    char* ws = (char*)d_ws;
    u16* Xb = (u16*)ws;                                   // 16 MB
    u16* Wb = (u16*)(ws + 16777216);                      // 6 MB
    u16* Qb = (u16*)(ws + 23068672);                      // 16 MB
    u16* Kb = (u16*)(ws + 39845888);                      // 16 MB
    u16* Vb = (u16*)(ws + 56623104);                      // 16 MB (V^T layout)

    cvt_all<<<2048, 256, 0, stream>>>(hs, wq, wk, wv, Xb, Wb);

    // XCD swizzle (T1): bid = nb*32 + mb -> all n-blocks of an A-panel on one XCD
    qkv_gemm<<<(N_TOT / 128) * (M_TOT / 256), 512, 0, stream>>>(
        Xb, Wb, bq, bk, bv, Qb, Kb, Vb);

    // XCD swizzle (T1): bid = qb*64 + head -> all q-blocks of a head on one XCD
    attn<<<(S_ / 256) * (B_ * NH_), 512, 0, stream>>>(Qb, Kb, Vb, mask, out);
}